// Round 1
// baseline (1812.613 us; speedup 1.0000x reference)
//
#include <hip/hip_runtime.h>

#define N_NODES 50000
#define N_EDGES 800000
#define IN_F 128
#define HID 128
#define NCLS 47

// ---------------------------------------------------------------------------
// 1) degree histograms via fp32 atomics (counts < 2^24 so fp32 exact)
__global__ void deg_kernel(const int* __restrict__ src, const int* __restrict__ dst,
                           float* __restrict__ deg_out, float* __restrict__ deg_in) {
    int e = blockIdx.x * blockDim.x + threadIdx.x;
    if (e < N_EDGES) {
        atomicAdd(&deg_out[src[e]], 1.0f);
        atomicAdd(&deg_in[dst[e]], 1.0f);
    }
}

// 2) in-place deg -> rsqrt(max(deg,1))
__global__ void norm_kernel(float* __restrict__ deg_out, float* __restrict__ deg_in) {
    int i = blockIdx.x * blockDim.x + threadIdx.x;
    if (i < N_NODES) {
        deg_out[i] = rsqrtf(fmaxf(deg_out[i], 1.0f));
        deg_in[i]  = rsqrtf(fmaxf(deg_in[i], 1.0f));
    }
}

// 3) H1[row,:] = (X[row,:] * norm_src[row]) @ W1   (one row per 128-thread block)
__global__ void gemm1_kernel(const float* __restrict__ X, const float* __restrict__ W1,
                             const float* __restrict__ norm_src, float* __restrict__ H) {
    __shared__ float xs[IN_F];
    int row = blockIdx.x;
    int t = threadIdx.x;
    xs[t] = X[row * IN_F + t] * norm_src[row];
    __syncthreads();
    float acc = 0.f;
#pragma unroll 8
    for (int k = 0; k < IN_F; ++k)
        acc += xs[k] * W1[k * HID + t];
    H[row * HID + t] = acc;
}

// 4) edge scatter: agg[dst,:] += H[src,:]   (thread = edge x float4-group)
__global__ void scatter1_kernel(const float* __restrict__ H, const int* __restrict__ src,
                                const int* __restrict__ dst, float* __restrict__ agg) {
    int tid = blockIdx.x * blockDim.x + threadIdx.x;   // < 800000*32 = 25.6M
    if (tid >= N_EDGES * 32) return;
    int e = tid >> 5;
    int g = (tid & 31) << 2;          // float4 group offset
    int s = src[e];
    int d = dst[e];
    const float4 v = *(const float4*)&H[s * IN_F + g];
    float* a = &agg[d * IN_F + g];
    atomicAdd(a + 0, v.x);
    atomicAdd(a + 1, v.y);
    atomicAdd(a + 2, v.z);
    atomicAdd(a + 3, v.w);
}

// 5) H2[row,:] = (relu(agg1[row,:]*norm_dst[row]+b1) * norm_src[row]) @ W2
//    one row per 64-thread block; 47 active output cols
__global__ void gemm2_kernel(const float* __restrict__ agg1, const float* __restrict__ W2,
                             const float* __restrict__ b1, const float* __restrict__ norm_src,
                             const float* __restrict__ norm_dst, float* __restrict__ H2) {
    __shared__ float hs[HID];
    int row = blockIdx.x;
    int t = threadIdx.x;
    float ns = norm_src[row], nd = norm_dst[row];
    for (int k = t; k < HID; k += 64) {
        float v = agg1[row * HID + k] * nd + b1[k];
        hs[k] = fmaxf(v, 0.f) * ns;
    }
    __syncthreads();
    if (t < NCLS) {
        float acc = 0.f;
#pragma unroll 8
        for (int k = 0; k < HID; ++k)
            acc += hs[k] * W2[k * NCLS + t];
        H2[row * NCLS + t] = acc;
    }
}

// 6) edge scatter layer 2: thread = edge x 64-slot (47 active)
__global__ void scatter2_kernel(const float* __restrict__ H2, const int* __restrict__ src,
                                const int* __restrict__ dst, float* __restrict__ agg) {
    int tid = blockIdx.x * blockDim.x + threadIdx.x;   // < 800000*64 = 51.2M
    int e = tid >> 6;
    int c = tid & 63;
    if (e >= N_EDGES || c >= NCLS) return;
    atomicAdd(&agg[dst[e] * NCLS + c], H2[src[e] * NCLS + c]);
}

// 7) out = agg2 * norm_dst + b2
__global__ void final_kernel(const float* __restrict__ agg2, const float* __restrict__ b2,
                             const float* __restrict__ norm_dst, float* __restrict__ out) {
    int tid = blockIdx.x * blockDim.x + threadIdx.x;
    if (tid < N_NODES * NCLS) {
        int i = tid / NCLS;
        int c = tid - i * NCLS;
        out[tid] = agg2[tid] * norm_dst[i] + b2[c];
    }
}

extern "C" void kernel_launch(void* const* d_in, const int* in_sizes, int n_in,
                              void* d_out, int out_size, void* d_ws, size_t ws_size,
                              hipStream_t stream) {
    const float* X  = (const float*)d_in[0];
    const int*   ei = (const int*)d_in[1];
    const float* W1 = (const float*)d_in[2];
    const float* b1 = (const float*)d_in[3];
    const float* W2 = (const float*)d_in[4];
    const float* b2 = (const float*)d_in[5];
    float* out = (float*)d_out;

    const int* src = ei;             // edge_index[0]
    const int* dst = ei + N_EDGES;   // edge_index[1]

    // workspace layout (floats):
    //   [0, N)            norm_src (deg_out -> rsqrt in place)
    //   [N, 2N)           norm_dst (deg_in  -> rsqrt in place)
    //   [2N, 2N+N*128)    H1   (later reused as H2, stride NCLS)
    //   [.., +N*128)      agg1 (later reused as agg2, stride NCLS)
    float* ws       = (float*)d_ws;
    float* norm_src = ws;
    float* norm_dst = ws + N_NODES;
    float* H1       = ws + 2 * N_NODES;
    float* agg1     = H1 + (size_t)N_NODES * IN_F;
    float* H2       = H1;    // N*47 <= N*128, GEMM2 reads agg1 writes here
    float* agg2     = agg1;  // reused after GEMM2 consumed agg1

    // zero degree accumulators + layer-1 aggregation buffer
    hipMemsetAsync(ws, 0, (size_t)2 * N_NODES * sizeof(float), stream);
    hipMemsetAsync(agg1, 0, (size_t)N_NODES * HID * sizeof(float), stream);

    deg_kernel<<<(N_EDGES + 255) / 256, 256, 0, stream>>>(src, dst, norm_src, norm_dst);
    norm_kernel<<<(N_NODES + 255) / 256, 256, 0, stream>>>(norm_src, norm_dst);

    gemm1_kernel<<<N_NODES, 128, 0, stream>>>(X, W1, norm_src, H1);
    scatter1_kernel<<<(N_EDGES * 32 + 255) / 256, 256, 0, stream>>>(H1, src, dst, agg1);

    gemm2_kernel<<<N_NODES, 64, 0, stream>>>(agg1, W2, b1, norm_src, norm_dst, H2);

    // zero layer-2 aggregation region (aliases agg1, safe: agg1 fully consumed)
    hipMemsetAsync(agg2, 0, (size_t)N_NODES * NCLS * sizeof(float), stream);
    scatter2_kernel<<<((size_t)N_EDGES * 64 + 255) / 256, 256, 0, stream>>>(H2, src, dst, agg2);

    final_kernel<<<(N_NODES * NCLS + 255) / 256, 256, 0, stream>>>(agg2, b2, norm_dst, out);
}

// Round 2
// 531.765 us; speedup vs baseline: 3.4087x; 3.4087x over previous
//
#include <hip/hip_runtime.h>

#define N_NODES 50000
#define N_EDGES 800000
#define IN_F 128
#define HID 128
#define NCLS 47
#define SCAN_T 1024
#define GEMM1_R 8   // rows per block in gemm1 (amortizes W1 L2 reads)

// ---------------------------------------------------------------------------
// 1) integer degree histograms (counts needed for CSR; converted to norms later)
__global__ void deg_kernel(const int* __restrict__ src, const int* __restrict__ dst,
                           int* __restrict__ cnt_out, int* __restrict__ cnt_in) {
    int e = blockIdx.x * blockDim.x + threadIdx.x;
    if (e < N_EDGES) {
        atomicAdd(&cnt_out[src[e]], 1);
        atomicAdd(&cnt_in[dst[e]], 1);
    }
}

// 2) counts -> rsqrt(max(deg,1)) norms
__global__ void norm_kernel(const int* __restrict__ cnt_out, const int* __restrict__ cnt_in,
                            float* __restrict__ norm_src, float* __restrict__ norm_dst) {
    int i = blockIdx.x * blockDim.x + threadIdx.x;
    if (i < N_NODES) {
        norm_src[i] = rsqrtf(fmaxf((float)cnt_out[i], 1.0f));
        norm_dst[i] = rsqrtf(fmaxf((float)cnt_in[i], 1.0f));
    }
}

// 3) exclusive prefix sum of cnt_in -> offsets[N+1]; also init cursor
//    single block, chunked: thread t owns a contiguous chunk of ~49 nodes
__global__ __launch_bounds__(SCAN_T) void scan_kernel(const int* __restrict__ counts,
                                                      int* __restrict__ offsets,
                                                      int* __restrict__ cursor) {
    __shared__ int part[SCAN_T];
    int t = threadIdx.x;
    const int chunk = (N_NODES + SCAN_T - 1) / SCAN_T;
    int lo = t * chunk, hi = min(lo + chunk, N_NODES);
    int s = 0;
    for (int i = lo; i < hi; ++i) s += counts[i];
    part[t] = s;
    __syncthreads();
    for (int off = 1; off < SCAN_T; off <<= 1) {
        int v = (t >= off) ? part[t - off] : 0;
        __syncthreads();
        part[t] += v;
        __syncthreads();
    }
    int run = part[t] - s;  // exclusive prefix of this chunk
    for (int i = lo; i < hi; ++i) {
        offsets[i] = run;
        cursor[i] = run;
        run += counts[i];
    }
    if (t == SCAN_T - 1) offsets[N_NODES] = part[t];
}

// 4) CSR fill: group src ids by dst (order within a dst is arbitrary)
__global__ void csr_fill_kernel(const int* __restrict__ src, const int* __restrict__ dst,
                                int* __restrict__ cursor, int* __restrict__ csr_src) {
    int e = blockIdx.x * blockDim.x + threadIdx.x;
    if (e < N_EDGES) {
        int pos = atomicAdd(&cursor[dst[e]], 1);
        csr_src[pos] = src[e];
    }
}

// 5) H1[row,:] = (X[row,:]*norm_src[row]) @ W1 ; GEMM1_R rows per 128-thread block
__global__ __launch_bounds__(128) void gemm1_kernel(const float* __restrict__ X,
                                                    const float* __restrict__ W1,
                                                    const float* __restrict__ norm_src,
                                                    float* __restrict__ H) {
    __shared__ float xs[GEMM1_R][IN_F];
    int row0 = blockIdx.x * GEMM1_R;
    int t = threadIdx.x;
#pragma unroll
    for (int r = 0; r < GEMM1_R; ++r)
        xs[r][t] = X[(size_t)(row0 + r) * IN_F + t] * norm_src[row0 + r];
    __syncthreads();
    float acc[GEMM1_R];
#pragma unroll
    for (int r = 0; r < GEMM1_R; ++r) acc[r] = 0.f;
    for (int k = 0; k < IN_F; ++k) {
        float w = W1[k * HID + t];
#pragma unroll
        for (int r = 0; r < GEMM1_R; ++r) acc[r] += xs[r][k] * w;
    }
#pragma unroll
    for (int r = 0; r < GEMM1_R; ++r)
        H[(size_t)(row0 + r) * HID + t] = acc[r];
}

// 6) fused: agg = sum_{s in N_in(row)} H1[s,:]; h = relu(agg*nd + b1)*ns; H2 = h @ W2
//    one node per 128-thread block
__global__ __launch_bounds__(128) void gather1_gemm2_kernel(
        const float* __restrict__ H1, const int* __restrict__ offsets,
        const int* __restrict__ csr_src, const float* __restrict__ W2,
        const float* __restrict__ b1, const float* __restrict__ norm_src,
        const float* __restrict__ norm_dst, float* __restrict__ H2) {
    __shared__ float hs[HID];
    int row = blockIdx.x;
    int t = threadIdx.x;
    int beg = offsets[row], end = offsets[row + 1];
    float acc = 0.f;
    for (int i = beg; i < end; ++i) {
        int s = csr_src[i];
        acc += H1[(size_t)s * HID + t];
    }
    float v = acc * norm_dst[row] + b1[t];
    hs[t] = fmaxf(v, 0.f) * norm_src[row];
    __syncthreads();
    if (t < NCLS) {
        float dot = 0.f;
#pragma unroll 8
        for (int k = 0; k < HID; ++k)
            dot += hs[k] * W2[k * NCLS + t];
        H2[(size_t)row * NCLS + t] = dot;
    }
}

// 7) fused: out[row,:] = (sum H2[s,:]) * norm_dst[row] + b2 ; one node per wave
__global__ __launch_bounds__(64) void gather2_final_kernel(
        const float* __restrict__ H2, const int* __restrict__ offsets,
        const int* __restrict__ csr_src, const float* __restrict__ b2,
        const float* __restrict__ norm_dst, float* __restrict__ out) {
    int row = blockIdx.x;
    int t = threadIdx.x;
    if (t >= NCLS) return;
    int beg = offsets[row], end = offsets[row + 1];
    float acc = 0.f;
    for (int i = beg; i < end; ++i) {
        int s = csr_src[i];
        acc += H2[(size_t)s * NCLS + t];
    }
    out[(size_t)row * NCLS + t] = acc * norm_dst[row] + b2[t];
}

extern "C" void kernel_launch(void* const* d_in, const int* in_sizes, int n_in,
                              void* d_out, int out_size, void* d_ws, size_t ws_size,
                              hipStream_t stream) {
    const float* X  = (const float*)d_in[0];
    const int*   ei = (const int*)d_in[1];
    const float* W1 = (const float*)d_in[2];
    const float* b1 = (const float*)d_in[3];
    const float* W2 = (const float*)d_in[4];
    const float* b2 = (const float*)d_in[5];
    float* out = (float*)d_out;

    const int* src = ei;
    const int* dst = ei + N_EDGES;

    // workspace layout (4-byte units)
    char* w = (char*)d_ws;
    int*   cnt_out  = (int*)w;                         w += N_NODES * 4;
    int*   cnt_in   = (int*)w;                         w += N_NODES * 4;
    float* norm_src = (float*)w;                       w += N_NODES * 4;
    float* norm_dst = (float*)w;                       w += N_NODES * 4;
    int*   offsets  = (int*)w;                         w += (N_NODES + 1) * 4;
    int*   cursor   = (int*)w;                         w += N_NODES * 4;
    int*   csr_src  = (int*)w;                         w += N_EDGES * 4;
    float* H1       = (float*)w;                       w += (size_t)N_NODES * HID * 4;
    float* H2       = (float*)w;                       w += (size_t)N_NODES * NCLS * 4;

    hipMemsetAsync(cnt_out, 0, (size_t)2 * N_NODES * sizeof(int), stream);

    deg_kernel<<<(N_EDGES + 255) / 256, 256, 0, stream>>>(src, dst, cnt_out, cnt_in);
    norm_kernel<<<(N_NODES + 255) / 256, 256, 0, stream>>>(cnt_out, cnt_in, norm_src, norm_dst);
    scan_kernel<<<1, SCAN_T, 0, stream>>>(cnt_in, offsets, cursor);
    csr_fill_kernel<<<(N_EDGES + 255) / 256, 256, 0, stream>>>(src, dst, cursor, csr_src);

    gemm1_kernel<<<(N_NODES + GEMM1_R - 1) / GEMM1_R, 128, 0, stream>>>(X, W1, norm_src, H1);
    gather1_gemm2_kernel<<<N_NODES, 128, 0, stream>>>(H1, offsets, csr_src, W2, b1,
                                                      norm_src, norm_dst, H2);
    gather2_final_kernel<<<N_NODES, 64, 0, stream>>>(H2, offsets, csr_src, b2, norm_dst, out);
}

// Round 3
// 319.394 us; speedup vs baseline: 5.6752x; 1.6649x over previous
//
#include <hip/hip_runtime.h>
#include <hip/hip_fp16.h>

#define N_NODES 50000
#define N_EDGES 800000
#define IN_F 128
#define HID 128
#define NCLS 47
#define H2S 48          // padded H2 row stride (halfs)
#define W2C 64          // padded W2 col count
#define NCH 196         // ceil(N_NODES/256) chunks for scan
#define TM 32           // rows per block in register-tiled GEMMs
#define XTS 40          // LDS stride for staged X^T (32 rows + 8 pad: b128-aligned, ~2-way banks)

struct __align__(8) h2x2 { __half2 a, b; };

// ---------------------------------------------------------------------------
__global__ __launch_bounds__(256) void deg_kernel(const int* __restrict__ src,
                                                  const int* __restrict__ dst,
                                                  int* __restrict__ cnt_out,
                                                  int* __restrict__ cnt_in) {
    int e = blockIdx.x * 256 + threadIdx.x;
    if (e < N_EDGES) {
        atomicAdd(&cnt_out[src[e]], 1);
        atomicAdd(&cnt_in[dst[e]], 1);
    }
}

__global__ __launch_bounds__(256) void norm_kernel(const int* __restrict__ cnt_out,
                                                   const int* __restrict__ cnt_in,
                                                   float* __restrict__ norm_src,
                                                   float* __restrict__ norm_dst) {
    int i = blockIdx.x * 256 + threadIdx.x;
    if (i < N_NODES) {
        norm_src[i] = rsqrtf(fmaxf((float)cnt_out[i], 1.0f));
        norm_dst[i] = rsqrtf(fmaxf((float)cnt_in[i], 1.0f));
    }
}

// --- 3-phase exclusive scan of cnt_in -> offsets/cursor --------------------
__global__ __launch_bounds__(256) void scan1_kernel(const int* __restrict__ cnt_in,
                                                    int* __restrict__ chunk_sums) {
    __shared__ int sm[256];
    int idx = blockIdx.x * 256 + threadIdx.x;
    sm[threadIdx.x] = (idx < N_NODES) ? cnt_in[idx] : 0;
    __syncthreads();
    for (int off = 128; off > 0; off >>= 1) {
        if (threadIdx.x < off) sm[threadIdx.x] += sm[threadIdx.x + off];
        __syncthreads();
    }
    if (threadIdx.x == 0) chunk_sums[blockIdx.x] = sm[0];
}

__global__ __launch_bounds__(256) void scan2_kernel(const int* __restrict__ chunk_sums,
                                                    int* __restrict__ chunk_base) {
    __shared__ int sm[256];
    int t = threadIdx.x;
    int v = (t < NCH) ? chunk_sums[t] : 0;
    sm[t] = v;
    __syncthreads();
    for (int off = 1; off < 256; off <<= 1) {
        int u = (t >= off) ? sm[t - off] : 0;
        __syncthreads();
        sm[t] += u;
        __syncthreads();
    }
    if (t < NCH) chunk_base[t] = sm[t] - v;   // exclusive
}

__global__ __launch_bounds__(256) void scan3_kernel(const int* __restrict__ cnt_in,
                                                    const int* __restrict__ chunk_base,
                                                    int* __restrict__ offsets,
                                                    int* __restrict__ cursor) {
    __shared__ int sm[256];
    int t = threadIdx.x;
    int idx = blockIdx.x * 256 + t;
    int v = (idx < N_NODES) ? cnt_in[idx] : 0;
    sm[t] = v;
    __syncthreads();
    for (int off = 1; off < 256; off <<= 1) {
        int u = (t >= off) ? sm[t - off] : 0;
        __syncthreads();
        sm[t] += u;
        __syncthreads();
    }
    if (idx < N_NODES) {
        int o = chunk_base[blockIdx.x] + sm[t] - v;
        offsets[idx] = o;
        cursor[idx] = o;
    }
    if (blockIdx.x == 0 && t == 0) offsets[N_NODES] = N_EDGES;
}

__global__ __launch_bounds__(256) void csr_fill_kernel(const int* __restrict__ src,
                                                       const int* __restrict__ dst,
                                                       int* __restrict__ cursor,
                                                       int* __restrict__ csr_src) {
    int e = blockIdx.x * 256 + threadIdx.x;
    if (e < N_EDGES) {
        int pos = atomicAdd(&cursor[dst[e]], 1);
        csr_src[pos] = src[e];
    }
}

// --- pad W2 [128][47] -> W2p [128][64] fp32 --------------------------------
__global__ __launch_bounds__(256) void pad_w2_kernel(const float* __restrict__ W2,
                                                     float* __restrict__ W2p) {
    int idx = blockIdx.x * 256 + threadIdx.x;   // < 128*64
    if (idx < HID * W2C) {
        int k = idx >> 6, c = idx & 63;
        W2p[idx] = (c < NCLS) ? W2[k * NCLS + c] : 0.f;
    }
}

// --- gemm1: H1h[row,:] = fp16( (X[row,:]*ns[row]) @ W1 ), 32 rows/block ----
__global__ __launch_bounds__(128) void gemm1_kernel(const float* __restrict__ X,
                                                    const float* __restrict__ W1,
                                                    const float* __restrict__ norm_src,
                                                    __half* __restrict__ H1h) {
    __shared__ __align__(16) float xs[IN_F * XTS];
    const int t = threadIdx.x;
    const int row0 = blockIdx.x * TM;
    // stage X^T (scaled by norm_src) into LDS: xs[k*XTS + r], r=0..31
#pragma unroll
    for (int i = 0; i < 8; ++i) {
        int id = t + 128 * i;
        int r = id & 31;
        int q = id >> 5;               // col group: cols 4q..4q+3
        int row = row0 + r;
        float4 v = make_float4(0.f, 0.f, 0.f, 0.f);
        float ns = 0.f;
        if (row < N_NODES) {
            v = *(const float4*)&X[(size_t)row * IN_F + 4 * q];
            ns = norm_src[row];
        }
        xs[(4 * q + 0) * XTS + r] = v.x * ns;
        xs[(4 * q + 1) * XTS + r] = v.y * ns;
        xs[(4 * q + 2) * XTS + r] = v.z * ns;
        xs[(4 * q + 3) * XTS + r] = v.w * ns;
    }
    __syncthreads();
    const int c = t & 31;              // cols 4c..4c+3
    const int rg = t >> 5;             // rows 4rg..4rg+3 (A) and +16 (B)
    float accA[4][4] = {{0.f}};
    float accB[4][4] = {{0.f}};
#pragma unroll 4
    for (int k = 0; k < IN_F; ++k) {
        const float4 w4 = *(const float4*)&W1[k * HID + 4 * c];
        const float4 a4 = *(const float4*)&xs[k * XTS + 4 * rg];
        const float4 b4 = *(const float4*)&xs[k * XTS + 16 + 4 * rg];
        const float wv[4] = {w4.x, w4.y, w4.z, w4.w};
        const float av[4] = {a4.x, a4.y, a4.z, a4.w};
        const float bv[4] = {b4.x, b4.y, b4.z, b4.w};
#pragma unroll
        for (int i = 0; i < 4; ++i)
#pragma unroll
            for (int j = 0; j < 4; ++j) {
                accA[i][j] += av[i] * wv[j];
                accB[i][j] += bv[i] * wv[j];
            }
    }
#pragma unroll
    for (int i = 0; i < 4; ++i) {
        int rowA = row0 + 4 * rg + i;
        int rowB = rowA + 16;
        if (rowA < N_NODES) {
            h2x2 p = {__floats2half2_rn(accA[i][0], accA[i][1]),
                      __floats2half2_rn(accA[i][2], accA[i][3])};
            *(h2x2*)&H1h[(size_t)rowA * HID + 4 * c] = p;
        }
        if (rowB < N_NODES) {
            h2x2 p = {__floats2half2_rn(accB[i][0], accB[i][1]),
                      __floats2half2_rn(accB[i][2], accB[i][3])};
            *(h2x2*)&H1h[(size_t)rowB * HID + 4 * c] = p;
        }
    }
}

// --- gather1: Hrelu[row,:] = relu( (sum H1h[s,:])*nd + b1 ) * ns -----------
// one node per wave, 4 nodes/block, 4-way edge unroll for MLP
__global__ __launch_bounds__(256) void gather1_kernel(const __half* __restrict__ H1h,
        const int* __restrict__ offsets, const int* __restrict__ csr_src,
        const float* __restrict__ b1, const float* __restrict__ norm_src,
        const float* __restrict__ norm_dst, float* __restrict__ Hrelu) {
    const int lane = threadIdx.x & 63;
    const int row = blockIdx.x * 4 + (threadIdx.x >> 6);
    const int beg = offsets[row], end = offsets[row + 1];
    float ax = 0.f, ay = 0.f;
    int i = beg;
    for (; i + 4 <= end; i += 4) {
        int s0 = csr_src[i], s1 = csr_src[i + 1], s2 = csr_src[i + 2], s3 = csr_src[i + 3];
        float2 f0 = __half22float2(*(const __half2*)&H1h[(size_t)s0 * HID + 2 * lane]);
        float2 f1 = __half22float2(*(const __half2*)&H1h[(size_t)s1 * HID + 2 * lane]);
        float2 f2 = __half22float2(*(const __half2*)&H1h[(size_t)s2 * HID + 2 * lane]);
        float2 f3 = __half22float2(*(const __half2*)&H1h[(size_t)s3 * HID + 2 * lane]);
        ax += (f0.x + f1.x) + (f2.x + f3.x);
        ay += (f0.y + f1.y) + (f2.y + f3.y);
    }
    for (; i < end; ++i) {
        float2 f = __half22float2(*(const __half2*)&H1h[(size_t)csr_src[i] * HID + 2 * lane]);
        ax += f.x;
        ay += f.y;
    }
    float nd = norm_dst[row], ns = norm_src[row];
    float2 bb = *(const float2*)&b1[2 * lane];
    float vx = fmaxf(ax * nd + bb.x, 0.f) * ns;
    float vy = fmaxf(ay * nd + bb.y, 0.f) * ns;
    *(float2*)&Hrelu[(size_t)row * HID + 2 * lane] = make_float2(vx, vy);
}

// --- gemm2: H2h[row, 0..47] = fp16( Hrelu[row,:] @ W2p ), 32 rows/block ----
__global__ __launch_bounds__(128) void gemm2_kernel(const float* __restrict__ Hrelu,
                                                    const float* __restrict__ W2p,
                                                    __half* __restrict__ H2h) {
    __shared__ __align__(16) float xs[HID * XTS];
    const int t = threadIdx.x;
    const int row0 = blockIdx.x * TM;
#pragma unroll
    for (int i = 0; i < 8; ++i) {
        int id = t + 128 * i;
        int r = id & 31;
        int q = id >> 5;
        int row = row0 + r;
        float4 v = make_float4(0.f, 0.f, 0.f, 0.f);
        if (row < N_NODES)
            v = *(const float4*)&Hrelu[(size_t)row * HID + 4 * q];
        xs[(4 * q + 0) * XTS + r] = v.x;
        xs[(4 * q + 1) * XTS + r] = v.y;
        xs[(4 * q + 2) * XTS + r] = v.z;
        xs[(4 * q + 3) * XTS + r] = v.w;
    }
    __syncthreads();
    const int c = t & 15;              // cols 4c..4c+3 (0..63)
    const int rg = t >> 4;             // rows 4rg..4rg+3 (0..31)
    float acc[4][4] = {{0.f}};
#pragma unroll 4
    for (int k = 0; k < HID; ++k) {
        const float4 w4 = *(const float4*)&W2p[k * W2C + 4 * c];
        const float4 a4 = *(const float4*)&xs[k * XTS + 4 * rg];
        const float wv[4] = {w4.x, w4.y, w4.z, w4.w};
        const float av[4] = {a4.x, a4.y, a4.z, a4.w};
#pragma unroll
        for (int i = 0; i < 4; ++i)
#pragma unroll
            for (int j = 0; j < 4; ++j)
                acc[i][j] += av[i] * wv[j];
    }
    if (c < 12) {                      // only cols 0..47 stored
#pragma unroll
        for (int i = 0; i < 4; ++i) {
            int row = row0 + 4 * rg + i;
            if (row < N_NODES) {
                h2x2 p = {__floats2half2_rn(acc[i][0], acc[i][1]),
                          __floats2half2_rn(acc[i][2], acc[i][3])};
                *(h2x2*)&H2h[(size_t)row * H2S + 4 * c] = p;
            }
        }
    }
}

// --- gather2: out[row,c] = (sum H2h[s,c])*nd + b2[c] -----------------------
__global__ __launch_bounds__(256) void gather2_kernel(const __half* __restrict__ H2h,
        const int* __restrict__ offsets, const int* __restrict__ csr_src,
        const float* __restrict__ b2, const float* __restrict__ norm_dst,
        float* __restrict__ out) {
    const int lane = threadIdx.x & 63;
    const int row = blockIdx.x * 4 + (threadIdx.x >> 6);
    if (lane >= H2S) return;
    const int beg = offsets[row], end = offsets[row + 1];
    float acc = 0.f;
    int i = beg;
    for (; i + 4 <= end; i += 4) {
        int s0 = csr_src[i], s1 = csr_src[i + 1], s2 = csr_src[i + 2], s3 = csr_src[i + 3];
        float f0 = __half2float(H2h[(size_t)s0 * H2S + lane]);
        float f1 = __half2float(H2h[(size_t)s1 * H2S + lane]);
        float f2 = __half2float(H2h[(size_t)s2 * H2S + lane]);
        float f3 = __half2float(H2h[(size_t)s3 * H2S + lane]);
        acc += (f0 + f1) + (f2 + f3);
    }
    for (; i < end; ++i)
        acc += __half2float(H2h[(size_t)csr_src[i] * H2S + lane]);
    if (lane < NCLS)
        out[(size_t)row * NCLS + lane] = acc * norm_dst[row] + b2[lane];
}

// ---------------------------------------------------------------------------
extern "C" void kernel_launch(void* const* d_in, const int* in_sizes, int n_in,
                              void* d_out, int out_size, void* d_ws, size_t ws_size,
                              hipStream_t stream) {
    const float* X  = (const float*)d_in[0];
    const int*   ei = (const int*)d_in[1];
    const float* W1 = (const float*)d_in[2];
    const float* b1 = (const float*)d_in[3];
    const float* W2 = (const float*)d_in[4];
    const float* b2 = (const float*)d_in[5];
    float* out = (float*)d_out;

    const int* src = ei;
    const int* dst = ei + N_EDGES;

    // bump allocator, 256B-aligned slots
    char* w = (char*)d_ws;
    auto alloc = [&](size_t bytes) {
        char* p = w;
        w += (bytes + 255) & ~(size_t)255;
        return p;
    };
    int*    cnt_out    = (int*)alloc(2 * N_NODES * 4);   // cnt_out + cnt_in contiguous
    int*    cnt_in     = cnt_out + N_NODES;
    float*  norm_src   = (float*)alloc(N_NODES * 4);
    float*  norm_dst   = (float*)alloc(N_NODES * 4);
    int*    offsets    = (int*)alloc((N_NODES + 1) * 4);
    int*    cursor     = (int*)alloc(N_NODES * 4);
    int*    csr_src    = (int*)alloc((size_t)N_EDGES * 4);
    int*    chunk_sums = (int*)alloc(NCH * 4);
    int*    chunk_base = (int*)alloc(NCH * 4);
    float*  W2p        = (float*)alloc((size_t)HID * W2C * 4);
    float*  Hrelu      = (float*)alloc((size_t)N_NODES * HID * 4);
    __half* H1h        = (__half*)alloc((size_t)N_NODES * HID * 2);
    __half* H2h        = (__half*)alloc((size_t)N_NODES * H2S * 2);

    hipMemsetAsync(cnt_out, 0, (size_t)2 * N_NODES * 4, stream);

    pad_w2_kernel<<<(HID * W2C + 255) / 256, 256, 0, stream>>>(W2, W2p);
    deg_kernel<<<N_EDGES / 256, 256, 0, stream>>>(src, dst, cnt_out, cnt_in);
    norm_kernel<<<NCH, 256, 0, stream>>>(cnt_out, cnt_in, norm_src, norm_dst);
    scan1_kernel<<<NCH, 256, 0, stream>>>(cnt_in, chunk_sums);
    scan2_kernel<<<1, 256, 0, stream>>>(chunk_sums, chunk_base);
    scan3_kernel<<<NCH, 256, 0, stream>>>(cnt_in, chunk_base, offsets, cursor);
    csr_fill_kernel<<<N_EDGES / 256, 256, 0, stream>>>(src, dst, cursor, csr_src);

    gemm1_kernel<<<(N_NODES + TM - 1) / TM, 128, 0, stream>>>(X, W1, norm_src, H1h);
    gather1_kernel<<<N_NODES / 4, 256, 0, stream>>>(H1h, offsets, csr_src, b1,
                                                    norm_src, norm_dst, Hrelu);
    gemm2_kernel<<<(N_NODES + TM - 1) / TM, 128, 0, stream>>>(Hrelu, W2p, H2h);
    gather2_kernel<<<N_NODES / 4, 256, 0, stream>>>(H2h, offsets, csr_src, b2,
                                                    norm_dst, out);
}